// Round 12
// baseline (170.184 us; speedup 1.0000x reference)
//
#include <hip/hip_runtime.h>
#include <math.h>

#define IN_DIM 64
#define HH 4
#define CC 128   /* HH*DD */
#define NEG_SLOPE 0.1f
#define CAP 4096 /* max edges per 128-node bucket held in LDS (mean 2046, 45 sd) */

typedef __attribute__((ext_vector_type(8))) short short8;
typedef __attribute__((ext_vector_type(4))) float f32x4;

__device__ __forceinline__ float leaky(float v) { return v >= 0.f ? v : NEG_SLOPE * v; }

__device__ __forceinline__ unsigned f2bf(float f) {
  unsigned u = __float_as_uint(f);
  unsigned r = u + 0x7FFFu + ((u >> 16) & 1u);
  return r >> 16;
}

// ---------------- Kernel 1: MFMA projection -> int8 feat (128B rows) + scale -------
// W swizzle-convert fused in-block (W is L2-resident, 32 KB).
__global__ __launch_bounds__(256) void k_project(
    const float* __restrict__ x, const float* __restrict__ W,
    const float* __restrict__ attn_l, const float* __restrict__ attn_r,
    unsigned char* __restrict__ featQ, float* __restrict__ scale,
    float* __restrict__ el, float* __restrict__ er, int N)
{
  __shared__ unsigned Wlds[4096];   // 16 KB swizzled Wt bf16
  __shared__ float Al[CC], Ar[CC];
  int t = threadIdx.x;
#pragma unroll
  for (int i = 0; i < 16; ++i) {
    int idx = t + 256 * i;          // 0..4095
    int nn = idx >> 5, r = idx & 31;
    int bb = r >> 2, h2 = r & 3;
    int kk = bb * 8 + h2 * 2;
    unsigned lo = f2bf(W[kk * CC + nn]);
    unsigned hi = f2bf(W[(kk + 1) * CC + nn]);
    Wlds[nn * 32 + (bb ^ (nn & 7)) * 4 + h2] = lo | (hi << 16);
  }
  if (t < CC) { Al[t] = attn_l[t]; Ar[t] = attn_r[t]; }
  __syncthreads();

  int lane = t & 63;
  int l4 = lane >> 4, l16 = lane & 15;
  int node = blockIdx.x * 64 + (t >> 6) * 16 + l16;
  bool valid = node < N;
  int nrow = valid ? node : 0;

  short8 bfr[2];
#pragma unroll
  for (int s = 0; s < 2; ++s) {
    const float4* xp = (const float4*)&x[(size_t)nrow * 64 + s * 32 + l4 * 8];
    float4 xa = xp[0], xb = xp[1];
    union { short8 v; unsigned u[4]; } pk;
    pk.u[0] = f2bf(xa.x) | (f2bf(xa.y) << 16);
    pk.u[1] = f2bf(xa.z) | (f2bf(xa.w) << 16);
    pk.u[2] = f2bf(xb.x) | (f2bf(xb.y) << 16);
    pk.u[3] = f2bf(xb.z) | (f2bf(xb.w) << 16);
    bfr[s] = pk.v;
  }

  f32x4 acc[8];
#pragma unroll
  for (int c = 0; c < 8; ++c) acc[c] = (f32x4){0.f, 0.f, 0.f, 0.f};

#pragma unroll
  for (int c = 0; c < 8; ++c) {
    int n0 = c * 16 + l16;
    int sw = n0 & 7;
#pragma unroll
    for (int s = 0; s < 2; ++s) {
      int b = s * 4 + l4;
      union { short8 v; uint4 q; } af;
      af.q = *(const uint4*)&Wlds[n0 * 32 + (b ^ sw) * 4];
      acc[c] = __builtin_amdgcn_mfma_f32_16x16x32_bf16(af.v, bfr[s], acc[c], 0, 0, 0);
    }
  }

  float mx = 0.f;
#pragma unroll
  for (int c = 0; c < 8; ++c) {
#pragma unroll
    for (int r = 0; r < 4; ++r) mx = fmaxf(mx, fabsf(acc[c][r]));
  }
  mx = fmaxf(mx, __shfl_xor(mx, 16, 64));
  mx = fmaxf(mx, __shfl_xor(mx, 32, 64));
  float mxs = fmaxf(mx, 1e-20f);
  float inv = 127.f / mxs;

  if (valid) {
#pragma unroll
    for (int c = 0; c < 8; ++c) {
      int q0 = __float2int_rn(acc[c][0] * inv) + 128;
      int q1 = __float2int_rn(acc[c][1] * inv) + 128;
      int q2 = __float2int_rn(acc[c][2] * inv) + 128;
      int q3 = __float2int_rn(acc[c][3] * inv) + 128;
      unsigned u = (unsigned)(q0 & 0xff) | ((unsigned)(q1 & 0xff) << 8) |
                   ((unsigned)(q2 & 0xff) << 16) | ((unsigned)(q3 & 0xff) << 24);
      *(unsigned*)&featQ[(size_t)node * 128 + c * 16 + l4 * 4] = u;
    }
    if (l4 == 0) scale[node] = mxs * (1.f / 127.f);
  }

  float pl[4], pr[4];
#pragma unroll
  for (int h = 0; h < 4; ++h) {
    float sl = 0.f, sr = 0.f;
#pragma unroll
    for (int ct = 0; ct < 2; ++ct) {
      int c = 2 * h + ct;
      int cb = c * 16 + l4 * 4;
#pragma unroll
      for (int r = 0; r < 4; ++r) {
        sl = fmaf(acc[c][r], Al[cb + r], sl);
        sr = fmaf(acc[c][r], Ar[cb + r], sr);
      }
    }
    sl += __shfl_xor(sl, 16, 64); sl += __shfl_xor(sl, 32, 64);
    sr += __shfl_xor(sr, 16, 64); sr += __shfl_xor(sr, 32, 64);
    pl[h] = sl; pr[h] = sr;
  }
  if (l4 == 0 && valid) {
    *(float4*)&el[(size_t)node * 4] = make_float4(pl[0], pl[1], pl[2], pl[3]);
    *(float4*)&er[(size_t)node * 4] = make_float4(pr[0], pr[1], pr[2], pr[3]);
  }
}

// ---------------- counting-sort (bucket = dst >> 7, 128 nodes/bucket) --------------
__global__ __launch_bounds__(256) void k_bhist(const int* __restrict__ dst,
                                               int* __restrict__ bcnt, int E, int NB) {
  __shared__ int lh[1024];
  for (int i = threadIdx.x; i < NB; i += 256) lh[i] = 0;
  __syncthreads();
  int stride = gridDim.x * 256;
  for (int i = blockIdx.x * 256 + threadIdx.x; i < E; i += stride)
    atomicAdd(&lh[dst[i] >> 7], 1);
  __syncthreads();
  for (int i = threadIdx.x; i < NB; i += 256) {
    int c = lh[i];
    if (c) atomicAdd(&bcnt[i], c);
  }
}

// scan over up to 1024 buckets: 512 threads x 2 elements
__global__ __launch_bounds__(512) void k_bscan(const int* __restrict__ bcnt,
                                               int* __restrict__ gbase,
                                               int* __restrict__ gcursor, int NB) {
  __shared__ int sh[512];
  int t = threadIdx.x;
  int i0 = 2 * t, i1 = 2 * t + 1;
  int v0 = (i0 < NB) ? bcnt[i0] : 0;
  int v1 = (i1 < NB) ? bcnt[i1] : 0;
  int s = v0 + v1;
  sh[t] = s;
  __syncthreads();
  for (int off = 1; off < 512; off <<= 1) {
    int a = (t >= off) ? sh[t - off] : 0;
    __syncthreads();
    sh[t] += a;
    __syncthreads();
  }
  int e = sh[t] - s;
  if (i0 < NB) { gbase[i0] = e;       gcursor[i0] = e; }
  if (i1 < NB) { gbase[i1] = e + v0;  gcursor[i1] = e + v0; }
}

// bin 8192 edges/block into buckets; payload = (src | dst_local<<20, w)
__global__ __launch_bounds__(512) void k_binA(const int* __restrict__ src,
                                              const int* __restrict__ dst,
                                              const float* __restrict__ w,
                                              int* __restrict__ gcursor,
                                              uint2* __restrict__ bkt, int E, int NB) {
  __shared__ int lh[1024];
  __shared__ int lbase[1024];
  int t = threadIdx.x;
  for (int i = t; i < NB; i += 512) lh[i] = 0;
  __syncthreads();
  long eb = (long)blockIdx.x * 8192;
  int b[16]; int r[16]; unsigned px[16]; unsigned pw[16];
#pragma unroll
  for (int i = 0; i < 16; ++i) {
    long e = eb + t + i * 512;
    bool v = e < E;
    int d = v ? dst[e] : 0;
    b[i] = d >> 7;
    px[i] = v ? ((unsigned)src[e] | ((unsigned)(d & 127) << 20)) : 0u;
    pw[i] = v ? ((const unsigned*)w)[e] : 0u;
    r[i] = v ? atomicAdd(&lh[b[i]], 1) : -1;
  }
  __syncthreads();
  for (int i = t; i < NB; i += 512) {
    int c = lh[i];
    lbase[i] = c ? atomicAdd(&gcursor[i], c) : 0;
  }
  __syncthreads();
#pragma unroll
  for (int i = 0; i < 16; ++i)
    if (r[i] >= 0) bkt[lbase[b[i]] + r[i]] = make_uint2(px[i], pw[i]);
}

// ---------------- Kernel 3: fused binB + softmax + int8 gather-sum -----------------
// block = one 128-node bucket. Phase 1-3: LDS CSR build. Phase 4: R11 aggregate.
__device__ __forceinline__ void fma16(float* acc, float& ka, float a, uint4 f) {
  ka += a;
  acc[0]  = fmaf(a, (float)( f.x        & 0xffu), acc[0]);
  acc[1]  = fmaf(a, (float)((f.x >> 8 ) & 0xffu), acc[1]);
  acc[2]  = fmaf(a, (float)((f.x >> 16) & 0xffu), acc[2]);
  acc[3]  = fmaf(a, (float)( f.x >> 24        ), acc[3]);
  acc[4]  = fmaf(a, (float)( f.y        & 0xffu), acc[4]);
  acc[5]  = fmaf(a, (float)((f.y >> 8 ) & 0xffu), acc[5]);
  acc[6]  = fmaf(a, (float)((f.y >> 16) & 0xffu), acc[6]);
  acc[7]  = fmaf(a, (float)( f.y >> 24        ), acc[7]);
  acc[8]  = fmaf(a, (float)( f.z        & 0xffu), acc[8]);
  acc[9]  = fmaf(a, (float)((f.z >> 8 ) & 0xffu), acc[9]);
  acc[10] = fmaf(a, (float)((f.z >> 16) & 0xffu), acc[10]);
  acc[11] = fmaf(a, (float)( f.z >> 24        ), acc[11]);
  acc[12] = fmaf(a, (float)( f.w        & 0xffu), acc[12]);
  acc[13] = fmaf(a, (float)((f.w >> 8 ) & 0xffu), acc[13]);
  acc[14] = fmaf(a, (float)((f.w >> 16) & 0xffu), acc[14]);
  acc[15] = fmaf(a, (float)( f.w >> 24        ), acc[15]);
}

__global__ __launch_bounds__(256) void k_binagg(
    const uint2* __restrict__ bkt, const int* __restrict__ bcnt,
    const int* __restrict__ gbase,
    const float* __restrict__ el, const float* __restrict__ er,
    const float* __restrict__ scale, const unsigned char* __restrict__ featQ,
    int2* __restrict__ spg, float* __restrict__ out, int N)
{
  __shared__ int  loffs[129];
  __shared__ int  lh[128], lcur[128];
  __shared__ int2 spl[CAP];
  __shared__ int    s_lds[4][64];
  __shared__ float4 a_lds[4][64];

  int b = blockIdx.x;
  int t = threadIdx.x;
  int base_b = gbase[b];
  int cnt_b = bcnt[b];
  bool ovf = cnt_b > CAP;

  // phase 1: node histogram
  if (t < 128) lh[t] = 0;
  __syncthreads();
  for (int e = t; e < cnt_b; e += 256) {
    uint2 p = bkt[base_b + e];
    atomicAdd(&lh[(p.x >> 20) & 127], 1);
  }
  __syncthreads();
  // phase 2: scan (threads 0..127)
  if (t < 128) lcur[t] = lh[t];
  __syncthreads();
  for (int off = 1; off < 128; off <<= 1) {
    int a = (t < 128 && t >= off) ? lcur[t - off] : 0;
    __syncthreads();
    if (t < 128) lcur[t] += a;
    __syncthreads();
  }
  if (t < 128) {
    loffs[t + 1] = lcur[t];
    if (t == 0) loffs[0] = 0;
  }
  __syncthreads();
  if (t < 128) lcur[t] = loffs[t];
  __syncthreads();
  // phase 3: scatter node-sorted payload to LDS (or global scratch on overflow)
  for (int e = t; e < cnt_b; e += 256) {
    uint2 p = bkt[base_b + e];
    int d = (p.x >> 20) & 127;
    int pos = atomicAdd(&lcur[d], 1);
    int2 v = make_int2((int)(p.x & 0xFFFFFu), (int)p.y);
    if (!ovf) spl[pos] = v; else spg[base_b + pos] = v;
  }
  __syncthreads();

  const int2* sps = ovf ? (spg + base_b) : (const int2*)spl;

  // phase 4: aggregate 128 nodes; 4 waves x 2 half-waves x 16 iters
  int lane = t & 63, wv = t >> 6;
  int half = lane >> 5, l32 = lane & 31;
  int grp = l32 >> 3;
  int c8 = l32 & 7;
  int hh = c8 >> 1;
  int hlane = lane & 32;
  const unsigned char* featl = featQ + c8 * 16;
  int* slf = &s_lds[wv][half * 32];
  const float* al = (const float*)&a_lds[wv][half * 32];

  for (int it = 0; it < 16; ++it) {
    int ln = it * 8 + wv * 2 + half;
    int n = (b << 7) + ln;
    if (n >= N) continue;
    int off0 = loffs[ln], off1 = loffs[ln + 1];
    int deg = off1 - off0;

    float acc[16];
#pragma unroll
    for (int i = 0; i < 16; ++i) acc[i] = 0.f;
    float ka = 0.f;

    if (deg > 0) {
      float4 erv = *reinterpret_cast<const float4*>(&er[(size_t)n * HH]);
      if (deg <= 32) {
        int dm1 = deg - 1;
        bool act = l32 < deg;
        int2 p = sps[off0 + (act ? l32 : 0)];
        int s = p.x;
        float wgt = __int_as_float(p.y);
        float sc = scale[s];

        // Phase A: issue gathers first
        uint4 fb[8];
#pragma unroll
        for (int k = 0; k < 4; ++k) {
          int ic = 4 * k + grp;
          int icc = ic < dm1 ? ic : dm1;
          int ss = __shfl(s, hlane + icc, 64);
          fb[k] = *reinterpret_cast<const uint4*>(featl + ((size_t)ss << 7));
        }
        if (deg > 16) {
#pragma unroll
          for (int k = 4; k < 8; ++k) {
            int ic = 4 * k + grp;
            int icc = ic < dm1 ? ic : dm1;
            int ss = __shfl(s, hlane + icc, 64);
            fb[k] = *reinterpret_cast<const uint4*>(featl + ((size_t)ss << 7));
          }
        }

        // Phase B: softmax (no max-sub) hides load latency
        float4 elv = *reinterpret_cast<const float4*>(&el[(size_t)s * HH]);
        float x0 = act ? __expf(leaky(elv.x + erv.x) * wgt) : 0.f;
        float x1 = act ? __expf(leaky(elv.y + erv.y) * wgt) : 0.f;
        float x2 = act ? __expf(leaky(elv.z + erv.z) * wgt) : 0.f;
        float x3 = act ? __expf(leaky(elv.w + erv.w) * wgt) : 0.f;
        float d0 = x0, d1 = x1, d2 = x2, d3 = x3;
#pragma unroll
        for (int d = 16; d >= 1; d >>= 1) {
          d0 += __shfl_xor(d0, d, 64);
          d1 += __shfl_xor(d1, d, 64);
          d2 += __shfl_xor(d2, d, 64);
          d3 += __shfl_xor(d3, d, 64);
        }
        float a0 = x0 * __builtin_amdgcn_rcpf(d0) * sc;
        float a1 = x1 * __builtin_amdgcn_rcpf(d1) * sc;
        float a2 = x2 * __builtin_amdgcn_rcpf(d2) * sc;
        float a3 = x3 * __builtin_amdgcn_rcpf(d3) * sc;
        a_lds[wv][half * 32 + l32] = make_float4(a0, a1, a2, a3);

        // Phase C: FMA
#pragma unroll
        for (int k = 0; k < 4; ++k) {
          int ic = 4 * k + grp;
          int icc = ic < dm1 ? ic : dm1;
          float a = (ic < deg) ? al[icc * 4 + hh] : 0.f;
          fma16(acc, ka, a, fb[k]);
        }
        if (deg > 16) {
#pragma unroll
          for (int k = 4; k < 8; ++k) {
            int ic = 4 * k + grp;
            int icc = ic < dm1 ? ic : dm1;
            float a = (ic < deg) ? al[icc * 4 + hh] : 0.f;
            fma16(acc, ka, a, fb[k]);
          }
        }
      } else {
        // chunked fallback (deg > 32): 3 passes over 32-edge chunks (rare)
        float m0 = -INFINITY, m1 = -INFINITY, m2 = -INFINITY, m3 = -INFINITY;
        for (int base = off0; base < off1; base += 32) {
          int j = base + l32;
          bool act = j < off1;
          int2 p = sps[act ? j : off0];
          float wgt = __int_as_float(p.y);
          float4 elv = *reinterpret_cast<const float4*>(&el[(size_t)p.x * HH]);
          float e0 = act ? leaky(elv.x + erv.x) * wgt : -INFINITY;
          float e1 = act ? leaky(elv.y + erv.y) * wgt : -INFINITY;
          float e2 = act ? leaky(elv.z + erv.z) * wgt : -INFINITY;
          float e3 = act ? leaky(elv.w + erv.w) * wgt : -INFINITY;
          m0 = fmaxf(m0, e0); m1 = fmaxf(m1, e1);
          m2 = fmaxf(m2, e2); m3 = fmaxf(m3, e3);
        }
#pragma unroll
        for (int d = 16; d >= 1; d >>= 1) {
          m0 = fmaxf(m0, __shfl_xor(m0, d, 64));
          m1 = fmaxf(m1, __shfl_xor(m1, d, 64));
          m2 = fmaxf(m2, __shfl_xor(m2, d, 64));
          m3 = fmaxf(m3, __shfl_xor(m3, d, 64));
        }
        float d0 = 0.f, d1 = 0.f, d2 = 0.f, d3 = 0.f;
        for (int base = off0; base < off1; base += 32) {
          int j = base + l32;
          bool act = j < off1;
          int2 p = sps[act ? j : off0];
          float wgt = __int_as_float(p.y);
          float4 elv = *reinterpret_cast<const float4*>(&el[(size_t)p.x * HH]);
          d0 += act ? __expf(leaky(elv.x + erv.x) * wgt - m0) : 0.f;
          d1 += act ? __expf(leaky(elv.y + erv.y) * wgt - m1) : 0.f;
          d2 += act ? __expf(leaky(elv.z + erv.z) * wgt - m2) : 0.f;
          d3 += act ? __expf(leaky(elv.w + erv.w) * wgt - m3) : 0.f;
        }
#pragma unroll
        for (int d = 16; d >= 1; d >>= 1) {
          d0 += __shfl_xor(d0, d, 64);
          d1 += __shfl_xor(d1, d, 64);
          d2 += __shfl_xor(d2, d, 64);
          d3 += __shfl_xor(d3, d, 64);
        }
        float i0 = __builtin_amdgcn_rcpf(d0), i1 = __builtin_amdgcn_rcpf(d1);
        float i2 = __builtin_amdgcn_rcpf(d2), i3 = __builtin_amdgcn_rcpf(d3);
        for (int base = off0; base < off1; base += 32) {
          int j = base + l32;
          bool act = j < off1;
          int2 p = sps[act ? j : off0];
          float wgt = __int_as_float(p.y);
          float sc = scale[p.x];
          float4 elv = *reinterpret_cast<const float4*>(&el[(size_t)p.x * HH]);
          float a0 = act ? __expf(leaky(elv.x + erv.x) * wgt - m0) * i0 * sc : 0.f;
          float a1 = act ? __expf(leaky(elv.y + erv.y) * wgt - m1) * i1 * sc : 0.f;
          float a2 = act ? __expf(leaky(elv.z + erv.z) * wgt - m2) * i2 * sc : 0.f;
          float a3 = act ? __expf(leaky(elv.w + erv.w) * wgt - m3) * i3 * sc : 0.f;
          slf[l32] = p.x << 7;
          a_lds[wv][half * 32 + l32] = make_float4(a0, a1, a2, a3);
          int cnt = off1 - base; if (cnt > 32) cnt = 32;
          int ne2 = (cnt + 3) >> 2;
          for (int b0 = 0; b0 < ne2; b0 += 4) {
            uint4 fb[4];
            float av[4];
#pragma unroll
            for (int k = 0; k < 4; ++k) {
              int idx = 4 * (b0 + k) + grp;
              bool vv = idx < cnt;
              int ic = vv ? idx : 0;
              av[k] = vv ? al[ic * 4 + hh] : 0.f;
              fb[k] = *reinterpret_cast<const uint4*>(featl + slf[ic]);
            }
#pragma unroll
            for (int k = 0; k < 4; ++k) fma16(acc, ka, av[k], fb[k]);
          }
        }
      }
    }
    // reduce across the 4 edge groups
#pragma unroll
    for (int d = 8; d <= 16; d <<= 1) {
#pragma unroll
      for (int i = 0; i < 16; ++i) acc[i] += __shfl_xor(acc[i], d, 64);
      ka += __shfl_xor(ka, d, 64);
    }
    if (grp == 0) {
      float base = 128.f * ka;
      float* orow = &out[(size_t)n * CC + c8 * 16];
#pragma unroll
      for (int k = 0; k < 4; ++k) {
        f32x4 o = {acc[4 * k] - base, acc[4 * k + 1] - base,
                   acc[4 * k + 2] - base, acc[4 * k + 3] - base};
        *reinterpret_cast<f32x4*>(orow + 4 * k) = o;
      }
    }
  }
}

// ---------------- launch ----------------
extern "C" void kernel_launch(void* const* d_in, const int* in_sizes, int n_in,
                              void* d_out, int out_size, void* d_ws, size_t ws_size,
                              hipStream_t stream)
{
  const float* x      = (const float*)d_in[1];
  const int*   src    = (const int*)d_in[2];
  const int*   dst    = (const int*)d_in[3];
  const float* w      = (const float*)d_in[4];
  const float* W_fc   = (const float*)d_in[5];
  const float* attn_l = (const float*)d_in[6];
  const float* attn_r = (const float*)d_in[7];
  float* out = (float*)d_out;

  int N = in_sizes[1] / IN_DIM;
  int E = in_sizes[2];
  int NB = (N + 127) / 128;   // 128 nodes/bucket; NB must be <= 1024

  char* p = (char*)d_ws;
  auto alloc = [&](size_t bytes) {
    char* r = p;
    p += (bytes + 255) & ~size_t(255);
    return r;
  };
  unsigned char* featQ = (unsigned char*)alloc((size_t)N * 128);
  float* scale = (float*)alloc((size_t)N * 4);
  float* el    = (float*)alloc((size_t)N * HH * 4);
  float* er    = (float*)alloc((size_t)N * HH * 4);
  int*   bcnt  = (int*)alloc(1024 * 4);
  int*   gbase = (int*)alloc(1024 * 4);
  int*   gcur  = (int*)alloc(1024 * 4);
  uint2* bkt   = (uint2*)alloc((size_t)E * 8);
  int2*  spg   = (int2*)alloc((size_t)E * 8);   // overflow scratch only

  hipMemsetAsync(bcnt, 0, 1024 * 4, stream);

  k_project<<<(N + 63) / 64, 256, 0, stream>>>(x, W_fc, attn_l, attn_r,
                                               featQ, scale, el, er, N);
  k_bhist<<<256, 256, 0, stream>>>(dst, bcnt, E, NB);
  k_bscan<<<1, 512, 0, stream>>>(bcnt, gbase, gcur, NB);
  k_binA<<<(E + 8191) / 8192, 512, 0, stream>>>(src, dst, w, gcur, bkt, E, NB);
  k_binagg<<<NB, 256, 0, stream>>>(bkt, bcnt, gbase, el, er, scale, featQ,
                                   spg, out, N);
}

// Round 13
// 143.750 us; speedup vs baseline: 1.1839x; 1.1839x over previous
//
#include <hip/hip_runtime.h>
#include <math.h>

#define IN_DIM 64
#define HH 4
#define CC 128   /* HH*DD */
#define NEG_SLOPE 0.1f

typedef __attribute__((ext_vector_type(8))) short short8;
typedef __attribute__((ext_vector_type(4))) float f32x4;

__device__ __forceinline__ float leaky(float v) { return v >= 0.f ? v : NEG_SLOPE * v; }

__device__ __forceinline__ unsigned f2bf(float f) {
  unsigned u = __float_as_uint(f);
  unsigned r = u + 0x7FFFu + ((u >> 16) & 1u);
  return r >> 16;
}

// ---------------- Kernel 0: build swizzled bf16 W^T image (128 rows x 32 u32) ------
__global__ void k_prepw(const float* __restrict__ W, unsigned* __restrict__ wt) {
  int tid = blockIdx.x * 256 + threadIdx.x;
  if (tid >= 128 * 32) return;
  int n = tid >> 5;
  int r = tid & 31;
  int b = r >> 2, h = r & 3;
  int k = b * 8 + h * 2;
  unsigned lo = f2bf(W[k * CC + n]);
  unsigned hi = f2bf(W[(k + 1) * CC + n]);
  wt[n * 32 + (b ^ (n & 7)) * 4 + h] = lo | (hi << 16);
}

// ---------------- Kernel 1: MFMA projection -> int8 feat (128B rows) + scale -------
__global__ __launch_bounds__(256) void k_project(
    const float* __restrict__ x, const unsigned* __restrict__ wt,
    const float* __restrict__ attn_l, const float* __restrict__ attn_r,
    unsigned char* __restrict__ featQ, float* __restrict__ scale,
    float* __restrict__ el, float* __restrict__ er, int N)
{
  __shared__ unsigned Wlds[4096];   // 16 KB swizzled Wt bf16
  __shared__ float Al[CC], Ar[CC];
  int t = threadIdx.x;
  {
    const uint4* s = (const uint4*)wt;
    uint4* d = (uint4*)Wlds;
#pragma unroll
    for (int i = 0; i < 4; ++i) d[t + 256 * i] = s[t + 256 * i];
  }
  if (t < CC) { Al[t] = attn_l[t]; Ar[t] = attn_r[t]; }
  __syncthreads();

  int lane = t & 63;
  int l4 = lane >> 4, l16 = lane & 15;
  int node = blockIdx.x * 64 + (t >> 6) * 16 + l16;
  bool valid = node < N;
  int nrow = valid ? node : 0;

  short8 bfr[2];
#pragma unroll
  for (int s = 0; s < 2; ++s) {
    const float4* xp = (const float4*)&x[(size_t)nrow * 64 + s * 32 + l4 * 8];
    float4 xa = xp[0], xb = xp[1];
    union { short8 v; unsigned u[4]; } pk;
    pk.u[0] = f2bf(xa.x) | (f2bf(xa.y) << 16);
    pk.u[1] = f2bf(xa.z) | (f2bf(xa.w) << 16);
    pk.u[2] = f2bf(xb.x) | (f2bf(xb.y) << 16);
    pk.u[3] = f2bf(xb.z) | (f2bf(xb.w) << 16);
    bfr[s] = pk.v;
  }

  f32x4 acc[8];
#pragma unroll
  for (int c = 0; c < 8; ++c) acc[c] = (f32x4){0.f, 0.f, 0.f, 0.f};

#pragma unroll
  for (int c = 0; c < 8; ++c) {
    int n0 = c * 16 + l16;
    int sw = n0 & 7;
#pragma unroll
    for (int s = 0; s < 2; ++s) {
      int b = s * 4 + l4;
      union { short8 v; uint4 q; } af;
      af.q = *(const uint4*)&Wlds[n0 * 32 + (b ^ sw) * 4];
      acc[c] = __builtin_amdgcn_mfma_f32_16x16x32_bf16(af.v, bfr[s], acc[c], 0, 0, 0);
    }
  }

  float mx = 0.f;
#pragma unroll
  for (int c = 0; c < 8; ++c) {
#pragma unroll
    for (int r = 0; r < 4; ++r) mx = fmaxf(mx, fabsf(acc[c][r]));
  }
  mx = fmaxf(mx, __shfl_xor(mx, 16, 64));
  mx = fmaxf(mx, __shfl_xor(mx, 32, 64));
  float mxs = fmaxf(mx, 1e-20f);
  float inv = 127.f / mxs;

  if (valid) {
#pragma unroll
    for (int c = 0; c < 8; ++c) {
      int q0 = __float2int_rn(acc[c][0] * inv) + 128;
      int q1 = __float2int_rn(acc[c][1] * inv) + 128;
      int q2 = __float2int_rn(acc[c][2] * inv) + 128;
      int q3 = __float2int_rn(acc[c][3] * inv) + 128;
      unsigned u = (unsigned)(q0 & 0xff) | ((unsigned)(q1 & 0xff) << 8) |
                   ((unsigned)(q2 & 0xff) << 16) | ((unsigned)(q3 & 0xff) << 24);
      *(unsigned*)&featQ[(size_t)node * 128 + c * 16 + l4 * 4] = u;
    }
    if (l4 == 0) scale[node] = mxs * (1.f / 127.f);
  }

  float pl[4], pr[4];
#pragma unroll
  for (int h = 0; h < 4; ++h) {
    float sl = 0.f, sr = 0.f;
#pragma unroll
    for (int ct = 0; ct < 2; ++ct) {
      int c = 2 * h + ct;
      int cb = c * 16 + l4 * 4;
#pragma unroll
      for (int r = 0; r < 4; ++r) {
        sl = fmaf(acc[c][r], Al[cb + r], sl);
        sr = fmaf(acc[c][r], Ar[cb + r], sr);
      }
    }
    sl += __shfl_xor(sl, 16, 64); sl += __shfl_xor(sl, 32, 64);
    sr += __shfl_xor(sr, 16, 64); sr += __shfl_xor(sr, 32, 64);
    pl[h] = sl; pr[h] = sr;
  }
  if (l4 == 0 && valid) {
    *(float4*)&el[(size_t)node * 4] = make_float4(pl[0], pl[1], pl[2], pl[3]);
    *(float4*)&er[(size_t)node * 4] = make_float4(pr[0], pr[1], pr[2], pr[3]);
  }
}

// ---------------- counting-sort CSR build (bucket = dst >> 8) ----------------
__global__ __launch_bounds__(256) void k_bhist(const int* __restrict__ dst,
                                               int* __restrict__ bcnt, int E, int NB) {
  __shared__ int lh[512];
  for (int i = threadIdx.x; i < NB; i += 256) lh[i] = 0;
  __syncthreads();
  int stride = gridDim.x * 256;
  for (int i = blockIdx.x * 256 + threadIdx.x; i < E; i += stride)
    atomicAdd(&lh[dst[i] >> 8], 1);
  __syncthreads();
  for (int i = threadIdx.x; i < NB; i += 256) {
    int c = lh[i];
    if (c) atomicAdd(&bcnt[i], c);
  }
}

__global__ __launch_bounds__(512) void k_bscan(const int* __restrict__ bcnt,
                                               int* __restrict__ gbase,
                                               int* __restrict__ gcursor, int NB) {
  __shared__ int sh[512];
  int t = threadIdx.x;
  int v = (t < NB) ? bcnt[t] : 0;
  sh[t] = v;
  __syncthreads();
  for (int off = 1; off < 512; off <<= 1) {
    int a = (t >= off) ? sh[t - off] : 0;
    __syncthreads();
    sh[t] += a;
    __syncthreads();
  }
  if (t < NB) {
    int e = sh[t] - v;
    gbase[t] = e;
    gcursor[t] = e;
  }
}

__global__ __launch_bounds__(512) void k_binA(const int* __restrict__ src,
                                              const int* __restrict__ dst,
                                              const float* __restrict__ w,
                                              int* __restrict__ gcursor,
                                              uint2* __restrict__ bkt, int E, int NB) {
  __shared__ int lh[512];
  __shared__ int lbase[512];
  int t = threadIdx.x;
  for (int i = t; i < NB; i += 512) lh[i] = 0;
  __syncthreads();
  long eb = (long)blockIdx.x * 8192;
  int b[16]; int r[16]; unsigned px[16]; unsigned pw[16];
#pragma unroll
  for (int i = 0; i < 16; ++i) {
    long e = eb + t + i * 512;
    bool v = e < E;
    int d = v ? dst[e] : 0;
    b[i] = d >> 8;
    px[i] = v ? ((unsigned)src[e] | ((unsigned)(d & 255) << 20)) : 0u;
    pw[i] = v ? ((const unsigned*)w)[e] : 0u;
    r[i] = v ? atomicAdd(&lh[b[i]], 1) : -1;
  }
  __syncthreads();
  for (int i = t; i < NB; i += 512) {
    int c = lh[i];
    lbase[i] = c ? atomicAdd(&gcursor[i], c) : 0;
  }
  __syncthreads();
#pragma unroll
  for (int i = 0; i < 16; ++i)
    if (r[i] >= 0) bkt[lbase[b[i]] + r[i]] = make_uint2(px[i], pw[i]);
}

__global__ __launch_bounds__(256) void k_binB(const uint2* __restrict__ bkt,
                                              const int* __restrict__ bcnt,
                                              const int* __restrict__ gbase,
                                              int* __restrict__ offs,
                                              int2* __restrict__ sp,
                                              int N, int E, int NB) {
  __shared__ int lh[256], sc[256], lcur[256];
  int b = blockIdx.x;
  int t = threadIdx.x;
  int base_b = gbase[b];
  int cnt_b = bcnt[b];
  lh[t] = 0;
  __syncthreads();
  for (int e = t; e < cnt_b; e += 256) {
    uint2 p = bkt[base_b + e];
    atomicAdd(&lh[(p.x >> 20) & 255], 1);
  }
  __syncthreads();
  int v = lh[t];
  sc[t] = v;
  __syncthreads();
  for (int off = 1; off < 256; off <<= 1) {
    int a = (t >= off) ? sc[t - off] : 0;
    __syncthreads();
    sc[t] += a;
    __syncthreads();
  }
  int excl = sc[t] - v;
  lcur[t] = excl;
  int n0 = b << 8;
  if (n0 + t < N) offs[n0 + t] = base_b + excl;
  if (b == NB - 1 && t == 0) offs[N] = E;
  __syncthreads();
  for (int e = t; e < cnt_b; e += 256) {
    uint2 p = bkt[base_b + e];
    int d = (p.x >> 20) & 255;
    int pos = atomicAdd(&lcur[d], 1);
    sp[base_b + pos] = make_int2((int)(p.x & 0xFFFFFu), (int)p.y);
  }
}

// ---------------- Kernel 3: softmax + int8 gather, 2-node pipelined half-wave ------
__device__ __forceinline__ void fma16(float* acc, float& ka, float a, uint4 f) {
  ka += a;
  acc[0]  = fmaf(a, (float)( f.x        & 0xffu), acc[0]);
  acc[1]  = fmaf(a, (float)((f.x >> 8 ) & 0xffu), acc[1]);
  acc[2]  = fmaf(a, (float)((f.x >> 16) & 0xffu), acc[2]);
  acc[3]  = fmaf(a, (float)( f.x >> 24        ), acc[3]);
  acc[4]  = fmaf(a, (float)( f.y        & 0xffu), acc[4]);
  acc[5]  = fmaf(a, (float)((f.y >> 8 ) & 0xffu), acc[5]);
  acc[6]  = fmaf(a, (float)((f.y >> 16) & 0xffu), acc[6]);
  acc[7]  = fmaf(a, (float)( f.y >> 24        ), acc[7]);
  acc[8]  = fmaf(a, (float)( f.z        & 0xffu), acc[8]);
  acc[9]  = fmaf(a, (float)((f.z >> 8 ) & 0xffu), acc[9]);
  acc[10] = fmaf(a, (float)((f.z >> 16) & 0xffu), acc[10]);
  acc[11] = fmaf(a, (float)( f.z >> 24        ), acc[11]);
  acc[12] = fmaf(a, (float)( f.w        & 0xffu), acc[12]);
  acc[13] = fmaf(a, (float)((f.w >> 8 ) & 0xffu), acc[13]);
  acc[14] = fmaf(a, (float)((f.w >> 16) & 0xffu), acc[14]);
  acc[15] = fmaf(a, (float)( f.w >> 24        ), acc[15]);
}

__global__ __launch_bounds__(256) void k_aggregate(
    const int* __restrict__ offs, const int2* __restrict__ sp,
    const float* __restrict__ el, const float* __restrict__ er,
    const float* __restrict__ scale, const unsigned char* __restrict__ featQ,
    float* __restrict__ out, int N)
{
  __shared__ int    s_lds[4][64];    // fallback path only
  __shared__ float4 a_lds[4][128];   // 2 nodes x 32 alphas per half-wave

  int t = threadIdx.x;
  int lane = t & 63, wv = t >> 6;
  int half = lane >> 5, l32 = lane & 31;
  int nb = blockIdx.x * 16 + (wv * 2 + half) * 2;   // this half-wave: nodes nb, nb+1
  if (nb >= N) return;

  int grp = l32 >> 3;
  int c8 = l32 & 7;
  int hh = c8 >> 1;
  int hlane = lane & 32;
  const unsigned char* featl = featQ + c8 * 16;
  int* slf = &s_lds[wv][half * 32];
  float4* aslot0 = &a_lds[wv][half * 64];
  float4* aslot1 = &a_lds[wv][half * 64 + 32];
  const float* al0 = (const float*)aslot0;
  const float* al1 = (const float*)aslot1;

  bool have1 = (nb + 1) < N;
  int off00 = offs[nb], off01 = offs[nb + 1];
  int deg0 = off01 - off00;
  int off10 = off01;
  int off11 = have1 ? offs[nb + 2] : off01;
  int deg1 = off11 - off10;

  float acc[16];
  float ka;

  if (deg0 <= 32 && deg1 <= 32) {
    // ================= pipelined dual-node fast path =================
    int s0 = 0, s1 = 0; float wgt0 = 0.f, wgt1 = 0.f, sc0 = 0.f, sc1 = 0.f;
    bool act0 = l32 < deg0, act1 = l32 < deg1;
    if (deg0 > 0) {
      int2 p = sp[off00 + (act0 ? l32 : 0)];
      s0 = p.x; wgt0 = __int_as_float(p.y); sc0 = scale[s0];
    }
    if (deg1 > 0) {
      int2 p = sp[off10 + (act1 ? l32 : 0)];
      s1 = p.x; wgt1 = __int_as_float(p.y); sc1 = scale[s1];
    }
    int dm10 = deg0 - 1, dm11 = deg1 - 1;

    // Phase A: issue ALL gathers for both nodes
    uint4 fb0[8], fb1[8];
    if (deg0 > 0) {
#pragma unroll
      for (int k = 0; k < 4; ++k) {
        int ic = 4 * k + grp;
        int icc = ic < dm10 ? ic : dm10;
        int ss = __shfl(s0, hlane + icc, 64);
        fb0[k] = *reinterpret_cast<const uint4*>(featl + ((size_t)ss << 7));
      }
      if (deg0 > 16) {
#pragma unroll
        for (int k = 4; k < 8; ++k) {
          int ic = 4 * k + grp;
          int icc = ic < dm10 ? ic : dm10;
          int ss = __shfl(s0, hlane + icc, 64);
          fb0[k] = *reinterpret_cast<const uint4*>(featl + ((size_t)ss << 7));
        }
      }
    }
    if (deg1 > 0) {
#pragma unroll
      for (int k = 0; k < 4; ++k) {
        int ic = 4 * k + grp;
        int icc = ic < dm11 ? ic : dm11;
        int ss = __shfl(s1, hlane + icc, 64);
        fb1[k] = *reinterpret_cast<const uint4*>(featl + ((size_t)ss << 7));
      }
      if (deg1 > 16) {
#pragma unroll
        for (int k = 4; k < 8; ++k) {
          int ic = 4 * k + grp;
          int icc = ic < dm11 ? ic : dm11;
          int ss = __shfl(s1, hlane + icc, 64);
          fb1[k] = *reinterpret_cast<const uint4*>(featl + ((size_t)ss << 7));
        }
      }
    }

    // Phase B: softmax node0, then node1 (hides load latency)
    if (deg0 > 0) {
      float4 erv = *reinterpret_cast<const float4*>(&er[(size_t)nb * HH]);
      float4 elv = *reinterpret_cast<const float4*>(&el[(size_t)s0 * HH]);
      float x0 = act0 ? __expf(leaky(elv.x + erv.x) * wgt0) : 0.f;
      float x1 = act0 ? __expf(leaky(elv.y + erv.y) * wgt0) : 0.f;
      float x2 = act0 ? __expf(leaky(elv.z + erv.z) * wgt0) : 0.f;
      float x3 = act0 ? __expf(leaky(elv.w + erv.w) * wgt0) : 0.f;
      float d0 = x0, d1 = x1, d2 = x2, d3 = x3;
#pragma unroll
      for (int d = 16; d >= 1; d >>= 1) {
        d0 += __shfl_xor(d0, d, 64);
        d1 += __shfl_xor(d1, d, 64);
        d2 += __shfl_xor(d2, d, 64);
        d3 += __shfl_xor(d3, d, 64);
      }
      aslot0[l32] = make_float4(x0 * __builtin_amdgcn_rcpf(d0) * sc0,
                                x1 * __builtin_amdgcn_rcpf(d1) * sc0,
                                x2 * __builtin_amdgcn_rcpf(d2) * sc0,
                                x3 * __builtin_amdgcn_rcpf(d3) * sc0);
    }
    if (deg1 > 0) {
      float4 erv = *reinterpret_cast<const float4*>(&er[(size_t)(nb + 1) * HH]);
      float4 elv = *reinterpret_cast<const float4*>(&el[(size_t)s1 * HH]);
      float x0 = act1 ? __expf(leaky(elv.x + erv.x) * wgt1) : 0.f;
      float x1 = act1 ? __expf(leaky(elv.y + erv.y) * wgt1) : 0.f;
      float x2 = act1 ? __expf(leaky(elv.z + erv.z) * wgt1) : 0.f;
      float x3 = act1 ? __expf(leaky(elv.w + erv.w) * wgt1) : 0.f;
      float d0 = x0, d1 = x1, d2 = x2, d3 = x3;
#pragma unroll
      for (int d = 16; d >= 1; d >>= 1) {
        d0 += __shfl_xor(d0, d, 64);
        d1 += __shfl_xor(d1, d, 64);
        d2 += __shfl_xor(d2, d, 64);
        d3 += __shfl_xor(d3, d, 64);
      }
      aslot1[l32] = make_float4(x0 * __builtin_amdgcn_rcpf(d0) * sc1,
                                x1 * __builtin_amdgcn_rcpf(d1) * sc1,
                                x2 * __builtin_amdgcn_rcpf(d2) * sc1,
                                x3 * __builtin_amdgcn_rcpf(d3) * sc1);
    }

    // Phase C0: FMA + store node0
#pragma unroll
    for (int i = 0; i < 16; ++i) acc[i] = 0.f;
    ka = 0.f;
    if (deg0 > 0) {
#pragma unroll
      for (int k = 0; k < 4; ++k) {
        int ic = 4 * k + grp;
        int icc = ic < dm10 ? ic : dm10;
        float a = (ic < deg0) ? al0[icc * 4 + hh] : 0.f;
        fma16(acc, ka, a, fb0[k]);
      }
      if (deg0 > 16) {
#pragma unroll
        for (int k = 4; k < 8; ++k) {
          int ic = 4 * k + grp;
          int icc = ic < dm10 ? ic : dm10;
          float a = (ic < deg0) ? al0[icc * 4 + hh] : 0.f;
          fma16(acc, ka, a, fb0[k]);
        }
      }
    }
#pragma unroll
    for (int d = 8; d <= 16; d <<= 1) {
#pragma unroll
      for (int i = 0; i < 16; ++i) acc[i] += __shfl_xor(acc[i], d, 64);
      ka += __shfl_xor(ka, d, 64);
    }
    if (grp == 0) {
      float base = 128.f * ka;
      float* orow = &out[(size_t)nb * CC + c8 * 16];
#pragma unroll
      for (int k = 0; k < 4; ++k) {
        f32x4 o = {acc[4 * k] - base, acc[4 * k + 1] - base,
                   acc[4 * k + 2] - base, acc[4 * k + 3] - base};
        *reinterpret_cast<f32x4*>(orow + 4 * k) = o;
      }
    }

    // Phase C1: FMA + store node1
#pragma unroll
    for (int i = 0; i < 16; ++i) acc[i] = 0.f;
    ka = 0.f;
    if (deg1 > 0) {
#pragma unroll
      for (int k = 0; k < 4; ++k) {
        int ic = 4 * k + grp;
        int icc = ic < dm11 ? ic : dm11;
        float a = (ic < deg1) ? al1[icc * 4 + hh] : 0.f;
        fma16(acc, ka, a, fb1[k]);
      }
      if (deg1 > 16) {
#pragma unroll
        for (int k = 4; k < 8; ++k) {
          int ic = 4 * k + grp;
          int icc = ic < dm11 ? ic : dm11;
          float a = (ic < deg1) ? al1[icc * 4 + hh] : 0.f;
          fma16(acc, ka, a, fb1[k]);
        }
      }
    }
#pragma unroll
    for (int d = 8; d <= 16; d <<= 1) {
#pragma unroll
      for (int i = 0; i < 16; ++i) acc[i] += __shfl_xor(acc[i], d, 64);
      ka += __shfl_xor(ka, d, 64);
    }
    if (grp == 0 && have1) {
      float base = 128.f * ka;
      float* orow = &out[(size_t)(nb + 1) * CC + c8 * 16];
#pragma unroll
      for (int k = 0; k < 4; ++k) {
        f32x4 o = {acc[4 * k] - base, acc[4 * k + 1] - base,
                   acc[4 * k + 2] - base, acc[4 * k + 3] - base};
        *reinterpret_cast<f32x4*>(orow + 4 * k) = o;
      }
    }
  } else {
    // ================= generic sequential path (rare: deg>32) =================
    for (int sel = 0; sel < 2; ++sel) {
      int n = nb + sel;
      if (n >= N) break;
      int off0 = sel ? off10 : off00;
      int off1 = sel ? off11 : off01;
      int deg = off1 - off0;

#pragma unroll
      for (int i = 0; i < 16; ++i) acc[i] = 0.f;
      ka = 0.f;

      if (deg > 0) {
        float4 erv = *reinterpret_cast<const float4*>(&er[(size_t)n * HH]);
        if (deg <= 32) {
          int dm1 = deg - 1;
          bool act = l32 < deg;
          int2 p = sp[off0 + (act ? l32 : 0)];
          int s = p.x;
          float wgt = __int_as_float(p.y);
          float sc = scale[s];
          uint4 fb[8];
#pragma unroll
          for (int k = 0; k < 4; ++k) {
            int ic = 4 * k + grp;
            int icc = ic < dm1 ? ic : dm1;
            int ss = __shfl(s, hlane + icc, 64);
            fb[k] = *reinterpret_cast<const uint4*>(featl + ((size_t)ss << 7));
          }
          if (deg > 16) {
#pragma unroll
            for (int k = 4; k < 8; ++k) {
              int ic = 4 * k + grp;
              int icc = ic < dm1 ? ic : dm1;
              int ss = __shfl(s, hlane + icc, 64);
              fb[k] = *reinterpret_cast<const uint4*>(featl + ((size_t)ss << 7));
            }
          }
          float4 elv = *reinterpret_cast<const float4*>(&el[(size_t)s * HH]);
          float x0 = act ? __expf(leaky(elv.x + erv.x) * wgt) : 0.f;
          float x1 = act ? __expf(leaky(elv.y + erv.y) * wgt) : 0.f;
          float x2 = act ? __expf(leaky(elv.z + erv.z) * wgt) : 0.f;
          float x3 = act ? __expf(leaky(elv.w + erv.w) * wgt) : 0.f;
          float d0 = x0, d1 = x1, d2 = x2, d3 = x3;
#pragma unroll
          for (int d = 16; d >= 1; d >>= 1) {
            d0 += __shfl_xor(d0, d, 64);
            d1 += __shfl_xor(d1, d, 64);
            d2 += __shfl_xor(d2, d, 64);
            d3 += __shfl_xor(d3, d, 64);
          }
          aslot0[l32] = make_float4(x0 * __builtin_amdgcn_rcpf(d0) * sc,
                                    x1 * __builtin_amdgcn_rcpf(d1) * sc,
                                    x2 * __builtin_amdgcn_rcpf(d2) * sc,
                                    x3 * __builtin_amdgcn_rcpf(d3) * sc);
#pragma unroll
          for (int k = 0; k < 4; ++k) {
            int ic = 4 * k + grp;
            int icc = ic < dm1 ? ic : dm1;
            float a = (ic < deg) ? al0[icc * 4 + hh] : 0.f;
            fma16(acc, ka, a, fb[k]);
          }
          if (deg > 16) {
#pragma unroll
            for (int k = 4; k < 8; ++k) {
              int ic = 4 * k + grp;
              int icc = ic < dm1 ? ic : dm1;
              float a = (ic < deg) ? al0[icc * 4 + hh] : 0.f;
              fma16(acc, ka, a, fb[k]);
            }
          }
        } else {
          // chunked (deg > 32): 3 passes over 32-edge chunks
          float m0 = -INFINITY, m1 = -INFINITY, m2 = -INFINITY, m3 = -INFINITY;
          for (int base = off0; base < off1; base += 32) {
            int j = base + l32;
            bool act = j < off1;
            int2 p = sp[act ? j : off0];
            float wgt = __int_as_float(p.y);
            float4 elv = *reinterpret_cast<const float4*>(&el[(size_t)p.x * HH]);
            float e0 = act ? leaky(elv.x + erv.x) * wgt : -INFINITY;
            float e1 = act ? leaky(elv.y + erv.y) * wgt : -INFINITY;
            float e2 = act ? leaky(elv.z + erv.z) * wgt : -INFINITY;
            float e3 = act ? leaky(elv.w + erv.w) * wgt : -INFINITY;
            m0 = fmaxf(m0, e0); m1 = fmaxf(m1, e1);
            m2 = fmaxf(m2, e2); m3 = fmaxf(m3, e3);
          }
#pragma unroll
          for (int d = 16; d >= 1; d >>= 1) {
            m0 = fmaxf(m0, __shfl_xor(m0, d, 64));
            m1 = fmaxf(m1, __shfl_xor(m1, d, 64));
            m2 = fmaxf(m2, __shfl_xor(m2, d, 64));
            m3 = fmaxf(m3, __shfl_xor(m3, d, 64));
          }
          float d0 = 0.f, d1 = 0.f, d2 = 0.f, d3 = 0.f;
          for (int base = off0; base < off1; base += 32) {
            int j = base + l32;
            bool act = j < off1;
            int2 p = sp[act ? j : off0];
            float wgt = __int_as_float(p.y);
            float4 elv = *reinterpret_cast<const float4*>(&el[(size_t)p.x * HH]);
            d0 += act ? __expf(leaky(elv.x + erv.x) * wgt - m0) : 0.f;
            d1 += act ? __expf(leaky(elv.y + erv.y) * wgt - m1) : 0.f;
            d2 += act ? __expf(leaky(elv.z + erv.z) * wgt - m2) : 0.f;
            d3 += act ? __expf(leaky(elv.w + erv.w) * wgt - m3) : 0.f;
          }
#pragma unroll
          for (int d = 16; d >= 1; d >>= 1) {
            d0 += __shfl_xor(d0, d, 64);
            d1 += __shfl_xor(d1, d, 64);
            d2 += __shfl_xor(d2, d, 64);
            d3 += __shfl_xor(d3, d, 64);
          }
          float i0 = __builtin_amdgcn_rcpf(d0), i1 = __builtin_amdgcn_rcpf(d1);
          float i2 = __builtin_amdgcn_rcpf(d2), i3 = __builtin_amdgcn_rcpf(d3);
          for (int base = off0; base < off1; base += 32) {
            int j = base + l32;
            bool act = j < off1;
            int2 p = sp[act ? j : off0];
            float wgt = __int_as_float(p.y);
            float sc = scale[p.x];
            float4 elv = *reinterpret_cast<const float4*>(&el[(size_t)p.x * HH]);
            float a0 = act ? __expf(leaky(elv.x + erv.x) * wgt - m0) * i0 * sc : 0.f;
            float a1 = act ? __expf(leaky(elv.y + erv.y) * wgt - m1) * i1 * sc : 0.f;
            float a2 = act ? __expf(leaky(elv.z + erv.z) * wgt - m2) * i2 * sc : 0.f;
            float a3 = act ? __expf(leaky(elv.w + erv.w) * wgt - m3) * i3 * sc : 0.f;
            slf[l32] = p.x << 7;
            aslot0[l32] = make_float4(a0, a1, a2, a3);
            int cnt = off1 - base; if (cnt > 32) cnt = 32;
            int ne2 = (cnt + 3) >> 2;
            for (int b0 = 0; b0 < ne2; b0 += 4) {
              uint4 fb[4];
              float av[4];
#pragma unroll
              for (int k = 0; k < 4; ++k) {
                int idx = 4 * (b0 + k) + grp;
                bool vv = idx < cnt;
                int ic = vv ? idx : 0;
                av[k] = vv ? al0[ic * 4 + hh] : 0.f;
                fb[k] = *reinterpret_cast<const uint4*>(featl + slf[ic]);
              }
#pragma unroll
              for (int k = 0; k < 4; ++k) fma16(acc, ka, av[k], fb[k]);
            }
          }
        }
      }
#pragma unroll
      for (int d = 8; d <= 16; d <<= 1) {
#pragma unroll
        for (int i = 0; i < 16; ++i) acc[i] += __shfl_xor(acc[i], d, 64);
        ka += __shfl_xor(ka, d, 64);
      }
      if (grp == 0) {
        float base = 128.f * ka;
        float* orow = &out[(size_t)n * CC + c8 * 16];
#pragma unroll
        for (int k = 0; k < 4; ++k) {
          f32x4 o = {acc[4 * k] - base, acc[4 * k + 1] - base,
                     acc[4 * k + 2] - base, acc[4 * k + 3] - base};
          *reinterpret_cast<f32x4*>(orow + 4 * k) = o;
        }
      }
    }
  }
}

// ---------------- launch ----------------
extern "C" void kernel_launch(void* const* d_in, const int* in_sizes, int n_in,
                              void* d_out, int out_size, void* d_ws, size_t ws_size,
                              hipStream_t stream)
{
  const float* x      = (const float*)d_in[1];
  const int*   src    = (const int*)d_in[2];
  const int*   dst    = (const int*)d_in[3];
  const float* w      = (const float*)d_in[4];
  const float* W_fc   = (const float*)d_in[5];
  const float* attn_l = (const float*)d_in[6];
  const float* attn_r = (const float*)d_in[7];
  float* out = (float*)d_out;

  int N = in_sizes[1] / IN_DIM;
  int E = in_sizes[2];
  int NB = (N + 255) / 256;   // nodes/bucket = 256; NB must be <= 512

  char* p = (char*)d_ws;
  auto alloc = [&](size_t bytes) {
    char* r = p;
    p += (bytes + 255) & ~size_t(255);
    return r;
  };
  unsigned char* featQ = (unsigned char*)alloc((size_t)N * 128);
  float* scale = (float*)alloc((size_t)N * 4);
  float* el    = (float*)alloc((size_t)N * HH * 4);
  float* er    = (float*)alloc((size_t)N * HH * 4);
  int*   offs  = (int*)alloc((size_t)(N + 1) * 4);
  int*   bcnt  = (int*)alloc(512 * 4);
  int*   gbase = (int*)alloc(512 * 4);
  int*   gcur  = (int*)alloc(512 * 4);
  unsigned* wtswz = (unsigned*)alloc(4096 * 4);
  uint2* bkt   = (uint2*)alloc((size_t)E * 8);
  int2*  sp    = (int2*)alloc((size_t)E * 8);

  hipMemsetAsync(bcnt, 0, 512 * 4, stream);

  k_prepw<<<16, 256, 0, stream>>>(W_fc, wtswz);
  k_project<<<(N + 63) / 64, 256, 0, stream>>>(x, wtswz, attn_l, attn_r,
                                               featQ, scale, el, er, N);
  k_bhist<<<256, 256, 0, stream>>>(dst, bcnt, E, NB);
  k_bscan<<<1, 512, 0, stream>>>(bcnt, gbase, gcur, NB);
  k_binA<<<(E + 8191) / 8192, 512, 0, stream>>>(src, dst, w, gcur, bkt, E, NB);
  k_binB<<<NB, 256, 0, stream>>>(bkt, bcnt, gbase, offs, sp, N, E, NB);
  k_aggregate<<<(N + 15) / 16, 256, 0, stream>>>(offs, sp, el, er, scale, featQ, out, N);
}